// Round 1
// baseline (163.217 us; speedup 1.0000x reference)
//
#include <hip/hip_runtime.h>

#define DEV __device__ __forceinline__

constexpr int D  = 2048;
constexpr int H  = 16;
constexpr int DH = 128;
constexpr int S  = 8192;
constexpr float EPS = 1e-6f;
constexpr float SCALE = 0.08838834764831845f; // DH^-0.5

typedef unsigned short ushortv4 __attribute__((ext_vector_type(4)));
typedef unsigned short ushortv8 __attribute__((ext_vector_type(8)));

DEV float bf2f(unsigned short u){ return __uint_as_float(((unsigned int)u) << 16); }
DEV unsigned short f2bf(float f){
  unsigned int x = __float_as_uint(f);
  unsigned int r = x + 0x7fffu + ((x >> 16) & 1u);
  return (unsigned short)(r >> 16);
}

// block-wide sum of two values; block = NW*64 threads
template<int NW>
DEV void block_sum2(float& a, float& b, float* buf){
  #pragma unroll
  for(int o = 32; o; o >>= 1){ a += __shfl_xor(a, o); b += __shfl_xor(b, o); }
  const int w = threadIdx.x >> 6;
  if((threadIdx.x & 63) == 0){ buf[w] = a; buf[NW + w] = b; }
  __syncthreads();
  a = buf[0]; b = buf[NW];
  #pragma unroll
  for(int i = 1; i < NW; i++){ a += buf[i]; b += buf[NW + i]; }
}

DEV float gelu(float x){
  float x3 = x * x * x;
  return 0.5f * x * (1.f + tanhf(0.7978845608028654f * (x + 0.044715f * x3)));
}

// ---------------- K1: LayerNorm all_toks -> n_all (bf16) ----------------
__global__ __launch_bounds__(256) void k_ln_all(const float* __restrict__ at,
    const float* __restrict__ g1, const float* __restrict__ b1,
    unsigned short* __restrict__ nall){
  __shared__ float buf[8];
  const int t = threadIdx.x;
  const size_t s = blockIdx.x;
  const float4* row = (const float4*)(at + s * D);
  float4 a = row[t], c = row[t + 256];
  float sum = a.x + a.y + a.z + a.w + c.x + c.y + c.z + c.w;
  float sq  = a.x*a.x + a.y*a.y + a.z*a.z + a.w*a.w
            + c.x*c.x + c.y*c.y + c.z*c.z + c.w*c.w;
  block_sum2<4>(sum, sq, buf);
  const float m = sum * (1.f / D);
  const float r = rsqrtf(sq * (1.f / D) - m * m + EPS);
  const float4* g4 = (const float4*)g1;
  const float4* b4 = (const float4*)b1;
  float4 ga = g4[t], gc = g4[t + 256], ba = b4[t], bc = b4[t + 256];
  ushortv4 oa, oc;
  oa[0] = f2bf((a.x - m) * r * ga.x + ba.x);
  oa[1] = f2bf((a.y - m) * r * ga.y + ba.y);
  oa[2] = f2bf((a.z - m) * r * ga.z + ba.z);
  oa[3] = f2bf((a.w - m) * r * ga.w + ba.w);
  oc[0] = f2bf((c.x - m) * r * gc.x + bc.x);
  oc[1] = f2bf((c.y - m) * r * gc.y + bc.y);
  oc[2] = f2bf((c.z - m) * r * gc.z + bc.z);
  oc[3] = f2bf((c.w - m) * r * gc.w + bc.w);
  ushortv4* dst = (ushortv4*)(nall + s * D);
  dst[t] = oa;
  dst[t + 256] = oc;
}

// ---------------- K2/K3: q = LN(self_tok) @ wq + bq ----------------
__global__ __launch_bounds__(256) void k_q_part(const float* __restrict__ self_tok,
    const float* __restrict__ g1, const float* __restrict__ b1,
    const float* __restrict__ wq, float* __restrict__ qpart){
  __shared__ float buf[8];
  __shared__ float sj[64];
  const int t = threadIdx.x, ic = blockIdx.x, jc = blockIdx.y;
  const float4* st = (const float4*)self_tok;
  float4 a = st[t], c = st[t + 256];
  float sum = a.x + a.y + a.z + a.w + c.x + c.y + c.z + c.w;
  float sq  = a.x*a.x + a.y*a.y + a.z*a.z + a.w*a.w
            + c.x*c.x + c.y*c.y + c.z*c.z + c.w*c.w;
  block_sum2<4>(sum, sq, buf);
  const float m = sum * (1.f / D);
  const float r = rsqrtf(sq * (1.f / D) - m * m + EPS);
  if(t < 64){
    int j = jc * 64 + t;
    float x = self_tok[j];
    sj[t] = (x - m) * r * g1[j] + b1[j];
  }
  __syncthreads();
  const int i = ic * 256 + t, j0 = jc * 64;
  float acc = 0.f;
  #pragma unroll 8
  for(int jj = 0; jj < 64; jj++)
    acc = fmaf(sj[jj], wq[(size_t)(j0 + jj) * D + i], acc);
  qpart[jc * D + i] = acc;
}

__global__ __launch_bounds__(256) void k_q_red(const float* __restrict__ qpart,
    const float* __restrict__ bq, float* __restrict__ q){
  const int i = blockIdx.x * 256 + threadIdx.x;
  float s = bq[i];
  #pragma unroll 8
  for(int jc = 0; jc < 32; jc++) s += qpart[jc * D + i];
  q[i] = s;
}

// ---------------- K4: wkq[j][h] = sum_dh wk[j, h*128+dh]*q[h*128+dh]; qb[h]=q.bk ----------------
__global__ __launch_bounds__(256) void k_wkq(const float* __restrict__ wk,
    const float* __restrict__ bk, const float* __restrict__ q,
    float* __restrict__ wkq, float* __restrict__ qb){
  const int j = blockIdx.x, t = threadIdx.x;
  const float* src = (j < D) ? (wk + (size_t)j * D) : bk;
  const float4* s4 = (const float4*)src;
  const float4* q4 = (const float4*)q;
  float4 a = s4[2 * t], c = s4[2 * t + 1], qa = q4[2 * t], qc = q4[2 * t + 1];
  float p = a.x*qa.x + a.y*qa.y + a.z*qa.z + a.w*qa.w
          + c.x*qc.x + c.y*qc.y + c.z*qc.z + c.w*qc.w;
  #pragma unroll
  for(int o = 1; o < 16; o <<= 1) p += __shfl_xor(p, o);
  if((t & 15) == 0){
    const int h = t >> 4;
    if(j < D) wkq[j * H + h] = p;
    else      qb[h] = p;
  }
}

// ---------------- K5: scores[h][s] = SCALE*(n_all[s,:] . wkq[:,h] + qb[h]) ----------------
__global__ __launch_bounds__(256) void k_scores(const unsigned short* __restrict__ nall,
    const float* __restrict__ wkq_g, const float* __restrict__ qb,
    float* __restrict__ scores){
  __shared__ float wkq_s[1024 * 16]; // 64 KB
  const int t = threadIdx.x;
  const int s0 = blockIdx.x * 32;
  const int h = t & 15, rr = t >> 4;
  float accA = 0.f, accB = 0.f;
  for(int c = 0; c < 2; c++){
    const int j0 = c * 1024;
    __syncthreads();
    const float4* srcv = (const float4*)(wkq_g + j0 * H);
    float4* dstv = (float4*)wkq_s;
    #pragma unroll
    for(int u = 0; u < 16; u++) dstv[t + 256 * u] = srcv[t + 256 * u];
    __syncthreads();
    const ushortv8* rowA = (const ushortv8*)(nall + (size_t)(s0 + rr) * D + j0);
    const ushortv8* rowB = (const ushortv8*)(nall + (size_t)(s0 + 16 + rr) * D + j0);
    for(int j8 = 0; j8 < 128; j8++){
      ushortv8 A = rowA[j8], B = rowB[j8];
      #pragma unroll
      for(int k = 0; k < 8; k++){
        float w = wkq_s[(j8 * 8 + k) * H + h];
        accA = fmaf(bf2f(A[k]), w, accA);
        accB = fmaf(bf2f(B[k]), w, accB);
      }
    }
  }
  const float qbh = qb[h];
  scores[h * S + s0 + rr]      = (accA + qbh) * SCALE;
  scores[h * S + s0 + 16 + rr] = (accB + qbh) * SCALE;
}

// ---------------- K6: softmax over S per head (unnormalized p + 1/sum) ----------------
__global__ __launch_bounds__(256) void k_softmax(const float* __restrict__ scores,
    float* __restrict__ p, float* __restrict__ inv_sum){
  __shared__ float mbuf[4], sbuf[4];
  const int h = blockIdx.x, t = threadIdx.x;
  const float* sc = scores + (size_t)h * S;
  float v[32];
  float mx = -3.0e38f;
  #pragma unroll
  for(int u = 0; u < 32; u++){ v[u] = sc[t + 256 * u]; mx = fmaxf(mx, v[u]); }
  #pragma unroll
  for(int o = 32; o; o >>= 1) mx = fmaxf(mx, __shfl_xor(mx, o));
  if((t & 63) == 0) mbuf[t >> 6] = mx;
  __syncthreads();
  mx = fmaxf(fmaxf(mbuf[0], mbuf[1]), fmaxf(mbuf[2], mbuf[3]));
  float sum = 0.f;
  float* pp = p + (size_t)h * S;
  #pragma unroll
  for(int u = 0; u < 32; u++){
    float e = __expf(v[u] - mx);
    pp[t + 256 * u] = e;
    sum += e;
  }
  #pragma unroll
  for(int o = 32; o; o >>= 1) sum += __shfl_xor(sum, o);
  if((t & 63) == 0) sbuf[t >> 6] = sum;
  __syncthreads();
  if(t == 0) inv_sum[h] = 1.f / (sbuf[0] + sbuf[1] + sbuf[2] + sbuf[3]);
}

// ---------------- K7/K8: a_ctx[h][j] = inv_sum[h] * sum_s p[h][s]*n_all[s][j] ----------------
__global__ __launch_bounds__(256) void k_actx_part(const unsigned short* __restrict__ nall,
    const float* __restrict__ p, float* __restrict__ part){
  __shared__ float pl[16 * 128]; // [h][ss]
  const int jc = blockIdx.x, sc = blockIdx.y, t = threadIdx.x;
  const int s0 = sc * 128, j = jc * 256 + t;
  #pragma unroll
  for(int u = 0; u < 8; u++){
    int idx = t + 256 * u;
    int hh = idx >> 7, ss = idx & 127;
    pl[idx] = p[(size_t)hh * S + s0 + ss];
  }
  __syncthreads();
  float acc[16];
  #pragma unroll
  for(int h = 0; h < 16; h++) acc[h] = 0.f;
  for(int ss = 0; ss < 128; ss++){
    float v = bf2f(nall[(size_t)(s0 + ss) * D + j]);
    #pragma unroll
    for(int h = 0; h < 16; h++) acc[h] = fmaf(pl[h * 128 + ss], v, acc[h]);
  }
  #pragma unroll
  for(int h = 0; h < 16; h++) part[((size_t)sc * 16 + h) * D + j] = acc[h];
}

__global__ __launch_bounds__(256) void k_actx_red(const float* __restrict__ part,
    const float* __restrict__ inv_sum, float* __restrict__ a_ctx){
  const int jc = blockIdx.x, h = blockIdx.y, t = threadIdx.x;
  const int j = jc * 256 + t;
  float s = 0.f;
  #pragma unroll 8
  for(int sc = 0; sc < 64; sc++) s += part[((size_t)sc * 16 + h) * D + j];
  a_ctx[h * D + j] = s * inv_sum[h];
}

// ---------------- K9/K10: out_attn[i] = bv[i] + sum_j a_ctx[h][j]*wv[j][i], i=h*128+dh ----------------
__global__ __launch_bounds__(128) void k_wv_part(const float* __restrict__ a_ctx,
    const float* __restrict__ wv, float* __restrict__ part){
  const int h = blockIdx.x, jc = blockIdx.y, t = threadIdx.x;
  const int i = h * DH + t, j0 = jc * 64;
  float acc = 0.f;
  #pragma unroll 8
  for(int jj = 0; jj < 64; jj++)
    acc = fmaf(a_ctx[h * D + j0 + jj], wv[(size_t)(j0 + jj) * D + i], acc);
  part[jc * D + i] = acc;
}

__global__ __launch_bounds__(256) void k_wv_red(const float* __restrict__ part,
    const float* __restrict__ bv, float* __restrict__ out_attn){
  const int i = blockIdx.x * 256 + threadIdx.x;
  float s = bv[i];
  #pragma unroll 8
  for(int jc = 0; jc < 32; jc++) s += part[jc * D + i];
  out_attn[i] = s;
}

// ---------------- K11: wo partials ----------------
__global__ __launch_bounds__(256) void k_wo_part(const float* __restrict__ out_attn,
    const float* __restrict__ wo, float* __restrict__ part){
  const int ic = blockIdx.x, jc = blockIdx.y, t = threadIdx.x;
  const int i = ic * 256 + t, j0 = jc * 64;
  float acc = 0.f;
  #pragma unroll 8
  for(int jj = 0; jj < 64; jj++)
    acc = fmaf(out_attn[j0 + jj], wo[(size_t)(j0 + jj) * D + i], acc);
  part[jc * D + i] = acc;
}

// ---------------- K12: x = self_tok + bo + sum(parts); x2 = LN(x)*g2+b2 ----------------
__global__ __launch_bounds__(1024) void k_x_ln2(const float* __restrict__ self_tok,
    const float* __restrict__ bo, const float* __restrict__ part_wo,
    const float* __restrict__ g2, const float* __restrict__ b2,
    float* __restrict__ x, float* __restrict__ x2){
  __shared__ float buf[32];
  const int t = threadIdx.x;
  float xv0, xv1;
  {
    float s = self_tok[t] + bo[t];
    #pragma unroll 8
    for(int jc = 0; jc < 32; jc++) s += part_wo[jc * D + t];
    xv0 = s; x[t] = s;
  }
  {
    const int i = t + 1024;
    float s = self_tok[i] + bo[i];
    #pragma unroll 8
    for(int jc = 0; jc < 32; jc++) s += part_wo[jc * D + i];
    xv1 = s; x[i] = s;
  }
  float sum = xv0 + xv1, sq = xv0 * xv0 + xv1 * xv1;
  block_sum2<16>(sum, sq, buf);
  const float m = sum * (1.f / D);
  const float r = rsqrtf(sq * (1.f / D) - m * m + EPS);
  x2[t]        = (xv0 - m) * r * g2[t] + b2[t];
  x2[t + 1024] = (xv1 - m) * r * g2[t + 1024] + b2[t + 1024];
}

// ---------------- K13/K14: h1 = gelu(x2 @ w_ffn1 + b_ffn1) ----------------
__global__ __launch_bounds__(256) void k_f1_part(const float* __restrict__ x2,
    const float* __restrict__ w1, float* __restrict__ part){
  const int oc = blockIdx.x, jc = blockIdx.y, t = threadIdx.x;
  const int o = oc * 256 + t, j0 = jc * 128;
  float acc = 0.f;
  #pragma unroll 8
  for(int jj = 0; jj < 128; jj++)
    acc = fmaf(x2[j0 + jj], w1[(size_t)(j0 + jj) * (4 * D) + o], acc);
  part[(size_t)jc * (4 * D) + o] = acc;
}

__global__ __launch_bounds__(256) void k_f1_red(const float* __restrict__ part,
    const float* __restrict__ b_f1, float* __restrict__ h1){
  const int o = blockIdx.x * 256 + threadIdx.x;
  float s = b_f1[o];
  #pragma unroll 8
  for(int jc = 0; jc < 16; jc++) s += part[(size_t)jc * (4 * D) + o];
  h1[o] = gelu(s);
}

// ---------------- K15/K16: out = x + h1 @ w_ffn2 + b_ffn2 ----------------
__global__ __launch_bounds__(256) void k_f2_part(const float* __restrict__ h1,
    const float* __restrict__ w2, float* __restrict__ part){
  const int ic = blockIdx.x, jc = blockIdx.y, t = threadIdx.x;
  const int i = ic * 256 + t, j0 = jc * 128;
  float acc = 0.f;
  #pragma unroll 8
  for(int jj = 0; jj < 128; jj++)
    acc = fmaf(h1[j0 + jj], w2[(size_t)(j0 + jj) * D + i], acc);
  part[jc * D + i] = acc;
}

__global__ __launch_bounds__(256) void k_final(const float* __restrict__ part,
    const float* __restrict__ x, const float* __restrict__ b_f2,
    float* __restrict__ out){
  const int i = blockIdx.x * 256 + threadIdx.x;
  float s = x[i] + b_f2[i];
  #pragma unroll 8
  for(int jc = 0; jc < 64; jc++) s += part[jc * D + i];
  out[i] = s;
}

extern "C" void kernel_launch(void* const* d_in, const int* in_sizes, int n_in,
                              void* d_out, int out_size, void* d_ws, size_t ws_size,
                              hipStream_t stream){
  const float* self_tok = (const float*)d_in[0];
  const float* all_toks = (const float*)d_in[1];
  const float* wq = (const float*)d_in[2];
  const float* bq = (const float*)d_in[3];
  const float* wk = (const float*)d_in[4];
  const float* bk = (const float*)d_in[5];
  const float* wv = (const float*)d_in[6];
  const float* bv = (const float*)d_in[7];
  const float* wo = (const float*)d_in[8];
  const float* bo = (const float*)d_in[9];
  const float* g1 = (const float*)d_in[10];
  const float* b1 = (const float*)d_in[11];
  const float* g2 = (const float*)d_in[12];
  const float* b2 = (const float*)d_in[13];
  const float* w1 = (const float*)d_in[14];
  const float* b_f1 = (const float*)d_in[15];
  const float* w2 = (const float*)d_in[16];
  const float* b_f2 = (const float*)d_in[17];
  float* out = (float*)d_out;

  char* wptr = (char*)d_ws;
  auto alloc = [&](size_t bytes) -> void* {
    void* p = (void*)wptr;
    wptr += (bytes + 255) & ~(size_t)255;
    return p;
  };
  unsigned short* n_all = (unsigned short*)alloc((size_t)S * D * 2);
  float* scores    = (float*)alloc((size_t)H * S * 4);
  float* attn      = (float*)alloc((size_t)H * S * 4);
  float* qpart     = (float*)alloc((size_t)32 * D * 4);
  float* q         = (float*)alloc((size_t)D * 4);
  float* qb        = (float*)alloc(64);
  float* inv_sum   = (float*)alloc(64);
  float* wkq       = (float*)alloc((size_t)D * H * 4);
  float* actx_part = (float*)alloc((size_t)64 * H * D * 4);
  float* a_ctx     = (float*)alloc((size_t)H * D * 4);
  float* part_wv   = (float*)alloc((size_t)32 * D * 4);
  float* out_attn  = (float*)alloc((size_t)D * 4);
  float* xbuf      = (float*)alloc((size_t)D * 4);
  float* x2        = (float*)alloc((size_t)D * 4);
  float* part_f1   = (float*)alloc((size_t)16 * 4 * D * 4);
  float* h1        = (float*)alloc((size_t)4 * D * 4);
  float* part_f2   = (float*)alloc((size_t)64 * D * 4);

  // attention path
  k_ln_all<<<S, 256, 0, stream>>>(all_toks, g1, b1, n_all);
  k_q_part<<<dim3(8, 32), 256, 0, stream>>>(self_tok, g1, b1, wq, qpart);
  k_q_red<<<8, 256, 0, stream>>>(qpart, bq, q);
  k_wkq<<<D + 1, 256, 0, stream>>>(wk, bk, q, wkq, qb);
  k_scores<<<S / 32, 256, 0, stream>>>(n_all, wkq, qb, scores);
  k_softmax<<<H, 256, 0, stream>>>(scores, attn, inv_sum);
  k_actx_part<<<dim3(8, 64), 256, 0, stream>>>(n_all, attn, actx_part);
  k_actx_red<<<dim3(8, 16), 256, 0, stream>>>(actx_part, inv_sum, a_ctx);
  k_wv_part<<<dim3(16, 32), 128, 0, stream>>>(a_ctx, wv, part_wv);
  k_wv_red<<<8, 256, 0, stream>>>(part_wv, bv, out_attn);
  k_wo_part<<<dim3(8, 32), 256, 0, stream>>>(out_attn, wo, part_wv /*reuse? no*/);
  // NOTE: reuse of part_wv for wo partials is safe: k_wv_red has consumed it
  // (same stream, in-order), and shapes match [32][D].
  k_x_ln2<<<1, 1024, 0, stream>>>(self_tok, bo, part_wv, g2, b2, xbuf, x2);
  // ffn
  k_f1_part<<<dim3(32, 16), 256, 0, stream>>>(x2, w1, part_f1);
  k_f1_red<<<32, 256, 0, stream>>>(part_f1, b_f1, h1);
  k_f2_part<<<dim3(8, 64), 256, 0, stream>>>(h1, w2, part_f2);
  k_final<<<8, 256, 0, stream>>>(part_f2, xbuf, b_f2, out);
}